// Round 3
// baseline (265.029 us; speedup 1.0000x reference)
//
#include <hip/hip_runtime.h>

#define KW 224          // padded K (bf16); row stride 448 B
#define NCH 7           // 7 chunks of 112 cols = 784
#define ROWS_TOTAL 131072

typedef float f32x4 __attribute__((ext_vector_type(4)));
typedef short s16x8 __attribute__((ext_vector_type(8)));

// bf16 copies, zero-padded K 196->224
__device__ unsigned short g_Wb[784 * KW];              // 351 KB
__device__ unsigned short g_xb[ROWS_TOTAL * KW];       // 58.7 MB (.bss)

__device__ __forceinline__ unsigned short f2bf(float f) {
    unsigned int u = __builtin_bit_cast(unsigned int, f);
    u += 0x7fffu + ((u >> 16) & 1u);          // round-to-nearest-even
    return (unsigned short)(u >> 16);
}

__global__ void prep_w(const float* __restrict__ W) {
    int t = blockIdx.x * 256 + threadIdx.x;   // 784 * 56 threads, 4 k each
    if (t >= 784 * 56) return;
    int col = t / 56;
    int k   = (t - col * 56) * 4;
    uint2 pk;
    if (k < 196) {
        f32x4 d = *(const f32x4*)(W + col * 196 + k);
        pk.x = (unsigned int)f2bf(d[0]) | ((unsigned int)f2bf(d[1]) << 16);
        pk.y = (unsigned int)f2bf(d[2]) | ((unsigned int)f2bf(d[3]) << 16);
    } else {
        pk.x = 0u; pk.y = 0u;
    }
    *(uint2*)(g_Wb + col * KW + k) = pk;
}

// patchify: x[32768,28,28] fp32 -> g_xb[131072][224] bf16 (patch rows, zero-padded)
__global__ void prep_x(const float* __restrict__ x) {
    const int NV = ROWS_TOTAL / 4 * 784 / 4;            // 6,422,528 float4s
    const f32x4* xv = (const f32x4*)x;
    for (int v = blockIdx.x * 256 + threadIdx.x; v < NV; v += gridDim.x * 256) {
        f32x4 d = xv[v];
        int F   = v * 4;
        int img = F / 784;
        int rem = F - img * 784;
        int h   = rem / 28;
        int w0  = rem - h * 28;          // in {0,4,...,24}
        int ph  = h / 14;
        int r   = h - ph * 14;
        int rowb = img * 4 + ph * 2;
        #pragma unroll
        for (int p = 0; p < 2; ++p) {
            int w  = w0 + 2 * p;         // even => bf16 pair stays inside one patch
            int pw = (w >= 14) ? 1 : 0;
            int c  = w - pw * 14;
            int row = rowb + pw;
            unsigned int pack = (unsigned int)f2bf(d[2 * p]) |
                                ((unsigned int)f2bf(d[2 * p + 1]) << 16);
            *(unsigned int*)((char*)g_xb + (size_t)row * (KW * 2) + (r * 14 + c) * 2) = pack;
        }
    }
    // zero pad k = 196..223 for every row: 131072 rows * 7 uint2
    for (int t = blockIdx.x * 256 + threadIdx.x; t < ROWS_TOTAL * 7; t += gridDim.x * 256) {
        int row = t / 7;
        int j   = t - row * 7;
        *(uint2*)((char*)g_xb + (size_t)row * (KW * 2) + 392 + j * 8) = (uint2){0u, 0u};
    }
}

// streaming GEMM: no LDS, no barriers. 4 waves/block, 32 rows/wave, all 784 cols.
__global__ __launch_bounds__(256, 3)
void patch_linear_mfma(const float* __restrict__ blin,
                       float* __restrict__ out) {
    const int tid  = threadIdx.x;
    const int l    = tid & 63;
    const int wv   = tid >> 6;          // wave 0..3
    const int lrow = l & 15;
    const int lko  = (l >> 4) * 16;     // byte offset of this lane's k-slice

    const int rowbase = blockIdx.x * 128 + wv * 32;
    const char* aBase = (const char*)g_xb + (size_t)(rowbase + lrow) * (KW * 2) + lko;
    const char* bBase = (const char*)g_Wb + (size_t)lrow * (KW * 2) + lko;

    for (int ch = 0; ch < NCH; ++ch) {
        const int nbase = ch * 112;
        const char* wChunk = bBase + (size_t)nbase * (KW * 2);

        float bias_r[7];
        #pragma unroll
        for (int n = 0; n < 7; ++n) bias_r[n] = blin[nbase + n * 16 + lrow];

        f32x4 acc[2][7];
        #pragma unroll
        for (int m = 0; m < 2; ++m)
            #pragma unroll
            for (int n = 0; n < 7; ++n)
                acc[m][n] = (f32x4){0.f, 0.f, 0.f, 0.f};

        #pragma unroll
        for (int kk = 0; kk < 7; ++kk) {
            s16x8 a0 = *(const s16x8*)(aBase + kk * 64);
            s16x8 a1 = *(const s16x8*)(aBase + 16 * (KW * 2) + kk * 64);
            s16x8 b[7];
            #pragma unroll
            for (int n = 0; n < 7; ++n)
                b[n] = *(const s16x8*)(wChunk + (size_t)n * 16 * (KW * 2) + kk * 64);
            #pragma unroll
            for (int n = 0; n < 7; ++n) {
                acc[0][n] = __builtin_amdgcn_mfma_f32_16x16x32_bf16(a0, b[n], acc[0][n], 0, 0, 0);
                acc[1][n] = __builtin_amdgcn_mfma_f32_16x16x32_bf16(a1, b[n], acc[1][n], 0, 0, 0);
            }
        }

        // store: each 16-lane group writes one aligned 64B line per (m,n,j)
        const int rgrp = (l >> 4) * 4;
        #pragma unroll
        for (int m = 0; m < 2; ++m) {
            size_t row0 = (size_t)rowbase + m * 16 + rgrp;
            #pragma unroll
            for (int n = 0; n < 7; ++n) {
                int col = nbase + n * 16 + lrow;
                #pragma unroll
                for (int j = 0; j < 4; ++j) {
                    out[(row0 + j) * 784 + col] = acc[m][n][j] + bias_r[n];
                }
            }
        }
    }
}

extern "C" void kernel_launch(void* const* d_in, const int* in_sizes, int n_in,
                              void* d_out, int out_size, void* d_ws, size_t ws_size,
                              hipStream_t stream) {
    const float* x    = (const float*)d_in[0];   // [32768,1,28,28]
    const float* Wlin = (const float*)d_in[1];   // [784,196]
    const float* blin = (const float*)d_in[2];   // [784]
    float* out = (float*)d_out;                  // [32768,4,784]

    prep_w<<<(784 * 56 + 255) / 256, 256, 0, stream>>>(Wlin);
    prep_x<<<4096, 256, 0, stream>>>(x);

    dim3 grid(ROWS_TOTAL / 128);                 // 1024 blocks
    dim3 block(256);
    patch_linear_mfma<<<grid, block, 0, stream>>>(blin, out);
}

// Round 4
// 217.607 us; speedup vs baseline: 1.2179x; 1.2179x over previous
//
#include <hip/hip_runtime.h>

#define KW 224          // padded K (bf16); row stride 448 B
#define ROWS_TOTAL 131072

typedef float f32x4 __attribute__((ext_vector_type(4)));
typedef short s16x8 __attribute__((ext_vector_type(8)));
typedef unsigned int u32x4 __attribute__((ext_vector_type(4)));

// bf16 copies, zero-padded K 196->224
__device__ unsigned short g_Wb[784 * KW];                       // 351 KB
__device__ unsigned short g_xb[(size_t)ROWS_TOTAL * KW];        // 58.7 MB

__device__ __forceinline__ unsigned short f2bf(float f) {
    unsigned int u = __builtin_bit_cast(unsigned int, f);
    u += 0x7fffu + ((u >> 16) & 1u);          // round-to-nearest-even
    return (unsigned short)(u >> 16);
}

__global__ void prep_w(const float* __restrict__ W) {
    int t = blockIdx.x * 256 + threadIdx.x;   // 784 * 56 threads, 4 k each
    if (t >= 784 * 56) return;
    int col = t / 56;
    int k   = (t - col * 56) * 4;
    uint2 pk;
    if (k < 196) {
        f32x4 d = *(const f32x4*)(W + col * 196 + k);
        pk.x = (unsigned int)f2bf(d[0]) | ((unsigned int)f2bf(d[1]) << 16);
        pk.y = (unsigned int)f2bf(d[2]) | ((unsigned int)f2bf(d[3]) << 16);
    } else {
        pk.x = 0u; pk.y = 0u;
    }
    *(uint2*)(g_Wb + col * KW + k) = pk;
}

// patchify: x[32768,28,28] fp32 -> g_xb[131072][224] bf16 (patch rows, zero-padded)
__global__ void prep_x(const float* __restrict__ x) {
    const int NV = ROWS_TOTAL / 4 * 784 / 4;            // 6,422,528 float4s
    const f32x4* xv = (const f32x4*)x;
    for (int v = blockIdx.x * 256 + threadIdx.x; v < NV; v += gridDim.x * 256) {
        f32x4 d = xv[v];
        int F   = v * 4;
        int img = F / 784;
        int rem = F - img * 784;
        int h   = rem / 28;
        int w0  = rem - h * 28;          // in {0,4,...,24}
        int ph  = h / 14;
        int r   = h - ph * 14;
        int rowb = img * 4 + ph * 2;
        #pragma unroll
        for (int p = 0; p < 2; ++p) {
            int w  = w0 + 2 * p;         // even => bf16 pair stays inside one patch
            int pw = (w >= 14) ? 1 : 0;
            int c  = w - pw * 14;
            int row = rowb + pw;
            unsigned int pack = (unsigned int)f2bf(d[2 * p]) |
                                ((unsigned int)f2bf(d[2 * p + 1]) << 16);
            *(unsigned int*)((char*)g_xb + (size_t)row * (KW * 2) + (r * 14 + c) * 2) = pack;
        }
    }
    // zero pad k = 196..223 for every row
    for (int t = blockIdx.x * 256 + threadIdx.x; t < ROWS_TOTAL * 7; t += gridDim.x * 256) {
        int row = t / 7;
        int j   = t - row * 7;
        *(uint2*)((char*)g_xb + (size_t)row * (KW * 2) + 392 + j * 8) = (uint2){0u, 0u};
    }
}

// Each wave: 16 FULL output rows x 784 cols (acc = 49 x f32x4, bias pre-init).
// A = W (rows -> out cols), B = x (rows -> out rows)  =>  lane stores dwordx4
// at out[rb + (l&15)][(l>>4)*4 + 16n] — wave writes 16 complete rows in one burst.
// W k-slice (784 cols x 32k = 50 KB) staged in LDS per k-step, shared by 4 waves.
__global__ __launch_bounds__(256, 2)
void patch_linear_mfma(const float* __restrict__ blin,
                       float* __restrict__ out) {
    __shared__ __align__(16) char sW[4 * 784 * 16];   // 50176 B, layout [ks][col*16B]

    const int tid  = threadIdx.x;
    const int l    = tid & 63;
    const int wv   = tid >> 6;          // wave 0..3
    const int lrow = l & 15;            // -> out row within wave's 16
    const int lk   = l >> 4;            // k sub-slice / out col group

    const int rb = blockIdx.x * 64 + wv * 16;

    // acc init = bias (MFMA C-in): acc[n][j] = blin[n*16 + lk*4 + j]
    f32x4 acc[49];
    #pragma unroll
    for (int n = 0; n < 49; ++n)
        acc[n] = *(const f32x4*)(blin + n * 16 + lk * 4);

    // staging addresses: chunk c = tid + i*256 -> col = c>>2, ks = c&3
    const char* wsrc = (const char*)g_Wb + (tid >> 2) * 448 + (tid & 3) * 16;
    char*       wdst = (char*)sW + (tid & 3) * 12544 + (tid >> 2) * 16;
    const char* xsrc = (const char*)g_xb + (size_t)(rb + lrow) * 448 + lk * 16;

    for (int kk = 0; kk < 7; ++kk) {
        // ---- stage W k-slice kk: 784 cols x 64B -> [ks][col*16] ----
        #pragma unroll
        for (int i = 0; i < 12; ++i) {
            u32x4 v = *(const u32x4*)(wsrc + i * 28672 + kk * 64);
            *(u32x4*)(wdst + i * 1024) = v;
        }
        if (tid < 64) {
            u32x4 v = *(const u32x4*)(wsrc + 12 * 28672 + kk * 64);
            *(u32x4*)(wdst + 12 * 1024) = v;
        }
        s16x8 xf = *(const s16x8*)(xsrc + kk * 64);   // overlaps barrier
        __syncthreads();

        // ---- 49 conflict-free ds_read_b128 + MFMA ----
        const char* aBase = (const char*)sW + lk * 12544 + lrow * 16;
        #pragma unroll
        for (int n = 0; n < 49; ++n) {
            s16x8 wf = *(const s16x8*)(aBase + n * 256);
            acc[n] = __builtin_amdgcn_mfma_f32_16x16x32_bf16(wf, xf, acc[n], 0, 0, 0);
        }
        __syncthreads();
    }

    // ---- store: 49 dwordx4, wave covers 16 complete rows (50 KB burst) ----
    float* orow = out + (size_t)(rb + lrow) * 784 + lk * 4;
    #pragma unroll
    for (int n = 0; n < 49; ++n)
        *(f32x4*)(orow + n * 16) = acc[n];
}

extern "C" void kernel_launch(void* const* d_in, const int* in_sizes, int n_in,
                              void* d_out, int out_size, void* d_ws, size_t ws_size,
                              hipStream_t stream) {
    const float* x    = (const float*)d_in[0];   // [32768,1,28,28]
    const float* Wlin = (const float*)d_in[1];   // [784,196]
    const float* blin = (const float*)d_in[2];   // [784]
    float* out = (float*)d_out;                  // [32768,4,784]

    prep_w<<<(784 * 56 + 255) / 256, 256, 0, stream>>>(Wlin);
    prep_x<<<4096, 256, 0, stream>>>(x);

    dim3 grid(ROWS_TOTAL / 64);                  // 2048 blocks
    dim3 block(256);
    patch_linear_mfma<<<grid, block, 0, stream>>>(blin, out);
}

// Round 5
// 204.752 us; speedup vs baseline: 1.2944x; 1.0628x over previous
//
#include <hip/hip_runtime.h>

#define KW 224              // padded K (bf16); g_Wb row stride 448 B
#define ROWS_TOTAL 131072
#define SXS 464             // sX row stride in bytes (232 bf16)

typedef float f32x4 __attribute__((ext_vector_type(4)));
typedef short s16x8 __attribute__((ext_vector_type(8)));

__device__ unsigned short g_Wb[784 * KW];   // 351 KB bf16, zero-padded K 196->224

__device__ __forceinline__ unsigned short f2bf(float f) {
    unsigned int u = __builtin_bit_cast(unsigned int, f);
    u += 0x7fffu + ((u >> 16) & 1u);        // round-to-nearest-even
    return (unsigned short)(u >> 16);
}

__global__ void prep_w(const float* __restrict__ W) {
    int t = blockIdx.x * 256 + threadIdx.x;   // 784 cols * 56 quads
    if (t >= 784 * 56) return;
    int col = t / 56;
    int k   = (t - col * 56) * 4;
    uint2 pk;
    if (k < 196) {
        f32x4 d = *(const f32x4*)(W + col * 196 + k);
        pk.x = (unsigned int)f2bf(d[0]) | ((unsigned int)f2bf(d[1]) << 16);
        pk.y = (unsigned int)f2bf(d[2]) | ((unsigned int)f2bf(d[3]) << 16);
    } else {
        pk.x = 0u; pk.y = 0u;
    }
    *(uint2*)(g_Wb + col * KW + k) = pk;
}

// async global -> LDS, 16 B per lane; LDS dest is wave-uniform base + lane*16
__device__ __forceinline__ void gload_lds16(void* lds, const void* g) {
    __builtin_amdgcn_global_load_lds(
        (const __attribute__((address_space(1))) unsigned int*)g,
        (__attribute__((address_space(3))) unsigned int*)lds, 16, 0, 0);
}

// 512 thr = 8 waves; block: 128 out rows (32 images) x all 784 cols.
// Wave w: 16 rows; lane holds out[rb+(l&15)][(l>>4)*4 + 16n] -> contiguous
// dwordx4 stores covering complete rows (write-combining friendly).
// W k-slice (50176 B) double-buffered in LDS via global_load_lds; one barrier
// per k-step; stage(kk+1) flies under compute(kk).
__global__ __launch_bounds__(512, 2)
void patch_linear_mfma(const float* __restrict__ x,
                       const float* __restrict__ blin,
                       float* __restrict__ out) {
    __shared__ __align__(16) char  sW[2][50176];        // [buf][chunk c*16B], c=col*4+ks
    __shared__ __align__(16) char  sX[128 * SXS];       // patch rows, bf16, padded

    const int tid  = threadIdx.x;
    const int l    = tid & 63;
    const int wv   = tid >> 6;          // 0..7
    const int lrow = l & 15;
    const int lk   = l >> 4;

    // ---------------- stage x: 32 images -> sX (patchify + bf16) ----------------
    const float* xb = x + (size_t)blockIdx.x * 32 * 784;
    const f32x4* xv = (const f32x4*)xb;
    for (int v = tid; v < 6272; v += 512) {
        f32x4 d = xv[v];
        int F   = v * 4;
        int img = F / 784;
        int rem = F - img * 784;
        int h   = rem / 28;
        int w0  = rem - h * 28;          // in {0,4,...,24}
        int ph  = h / 14;
        int r   = h - ph * 14;
        int rowb = img * 4 + ph * 2;
        #pragma unroll
        for (int p = 0; p < 2; ++p) {
            int w  = w0 + 2 * p;         // even => bf16 pair stays inside one patch
            int pw = (w >= 14) ? 1 : 0;
            int c  = w - pw * 14;
            int row = rowb + pw;
            unsigned int pack = (unsigned int)f2bf(d[2 * p]) |
                                ((unsigned int)f2bf(d[2 * p + 1]) << 16);
            *(unsigned int*)(sX + row * SXS + (r * 14 + c) * 2) = pack;
        }
    }
    for (int t = tid; t < 128 * 7; t += 512) {   // zero pad k = 196..223
        int row = t / 7;
        int j   = t - row * 7;
        *(uint2*)(sX + row * SXS + 392 + j * 8) = (uint2){0u, 0u};
    }

    // ---------------- W staging (async, double-buffered) ----------------
    // chunk c = i*512 + tid -> col = c>>2, ks = c&3
    // global src  = g_Wb + col*448 + ks*16 + kk*64   (per-lane)
    // lds dest    = sW[buf] + c*16                   (wave-uniform + lane*16)
    const char* wsrc = (const char*)g_Wb + (tid >> 2) * 448 + (tid & 3) * 16;
    auto stageW = [&](int buf, int kk) {
        const char* s = wsrc + kk * 64;
        char*       d = sW[buf] + wv * 1024;
        #pragma unroll
        for (int i = 0; i < 6; ++i)
            gload_lds16(d + i * 8192, s + i * 57344);
        if (wv == 0)                      // tail: cols 768..783
            gload_lds16(d + 6 * 8192, s + 6 * 57344);
    };

    stageW(0, 0);

    // acc init = bias: acc[n][j] = blin[n*16 + lk*4 + j]
    f32x4 acc[49];
    #pragma unroll
    for (int n = 0; n < 49; ++n)
        acc[n] = *(const f32x4*)(blin + n * 16 + lk * 4);

    __syncthreads();   // sX + buf0 ready (drains vmcnt)

    const char* xbase = sX + (wv * 16 + lrow) * SXS + lk * 16;

    for (int kk = 0; kk < 7; ++kk) {
        if (kk < 6) stageW((kk + 1) & 1, kk + 1);   // async, other buffer
        s16x8 xf = *(const s16x8*)(xbase + kk * 64);
        const char* aBase = sW[kk & 1] + lrow * 64 + lk * 16;
        #pragma unroll
        for (int n = 0; n < 49; ++n) {
            s16x8 wf = *(const s16x8*)(aBase + n * 1024);
            acc[n] = __builtin_amdgcn_mfma_f32_16x16x32_bf16(wf, xf, acc[n], 0, 0, 0);
        }
        __syncthreads();   // drains stage(kk+1); protects buffer reuse
    }

    // ---------------- store: wave writes 16 complete rows (50 KB burst) --------
    const int rb = blockIdx.x * 128 + wv * 16;
    float* orow = out + (size_t)(rb + lrow) * 784 + lk * 4;
    #pragma unroll
    for (int n = 0; n < 49; ++n)
        *(f32x4*)(orow + n * 16) = acc[n];
}

extern "C" void kernel_launch(void* const* d_in, const int* in_sizes, int n_in,
                              void* d_out, int out_size, void* d_ws, size_t ws_size,
                              hipStream_t stream) {
    const float* x    = (const float*)d_in[0];   // [32768,1,28,28]
    const float* Wlin = (const float*)d_in[1];   // [784,196]
    const float* blin = (const float*)d_in[2];   // [784]
    float* out = (float*)d_out;                  // [32768,4,784]

    prep_w<<<(784 * 56 + 255) / 256, 256, 0, stream>>>(Wlin);

    dim3 grid(ROWS_TOTAL / 128);                 // 1024 blocks
    dim3 block(512);
    patch_linear_mfma<<<grid, block, 0, stream>>>(x, blin, out);
}

// Round 6
// 183.667 us; speedup vs baseline: 1.4430x; 1.1148x over previous
//
#include <hip/hip_runtime.h>

#define ROWS_TOTAL 131072
#define XST 232             // g_xb / sX row stride in bf16 elements (464 B)

typedef float f32x4 __attribute__((ext_vector_type(4)));
typedef short s16x8 __attribute__((ext_vector_type(8)));

// W pre-arranged as the exact LDS image, per 112-col group:
//   byte addr = ((group*7 + kk)*4 + ks)*112*16 + col112*16 + e   (7 groups x 50176 B)
__device__ unsigned short g_Wb2[7 * 25088];
// x patchified, bf16, row stride 232 (zero-padded k = 196..231)
__device__ unsigned short g_xb[(size_t)ROWS_TOTAL * XST];

__device__ __forceinline__ unsigned short f2bf(float f) {
    unsigned int u = __builtin_bit_cast(unsigned int, f);
    u += 0x7fffu + ((u >> 16) & 1u);        // round-to-nearest-even
    return (unsigned short)(u >> 16);
}

__global__ void prep_w(const float* __restrict__ W) {
    int t = blockIdx.x * 256 + threadIdx.x;   // 784 cols * 56 k-quads
    if (t >= 784 * 56) return;
    int col = t / 56;
    int k0  = (t - col * 56) * 4;
    uint2 pk;
    if (k0 < 196) {
        f32x4 d = *(const f32x4*)(W + col * 196 + k0);
        pk.x = (unsigned int)f2bf(d[0]) | ((unsigned int)f2bf(d[1]) << 16);
        pk.y = (unsigned int)f2bf(d[2]) | ((unsigned int)f2bf(d[3]) << 16);
    } else {
        pk.x = 0u; pk.y = 0u;
    }
    int group = col / 112, col112 = col - group * 112;
    int kk = k0 >> 5, rem = k0 & 31, ks = rem >> 3, e0 = rem & 7;
    // ushort index: chunk*8 + e0
    size_t di = (size_t)((((group * 7 + kk) * 4 + ks) * 112) + col112) * 8 + e0;
    *(uint2*)(g_Wb2 + di) = pk;
}

// patchify: x[32768,28,28] fp32 -> g_xb[131072][232] bf16 (zero-padded)
__global__ void prep_x(const float* __restrict__ x) {
    const int NV = ROWS_TOTAL / 4 * 784 / 4;            // 6,422,528 float4s
    const f32x4* xv = (const f32x4*)x;
    for (int v = blockIdx.x * 256 + threadIdx.x; v < NV; v += gridDim.x * 256) {
        f32x4 d = xv[v];
        int F   = v * 4;
        int img = F / 784;
        int rem = F - img * 784;
        int h   = rem / 28;
        int w0  = rem - h * 28;          // in {0,4,...,24}
        int ph  = h / 14;
        int r   = h - ph * 14;
        int rowb = img * 4 + ph * 2;
        #pragma unroll
        for (int p = 0; p < 2; ++p) {
            int w  = w0 + 2 * p;         // even => bf16 pair stays inside one patch
            int pw = (w >= 14) ? 1 : 0;
            int c  = w - pw * 14;
            int row = rowb + pw;
            unsigned int pack = (unsigned int)f2bf(d[2 * p]) |
                                ((unsigned int)f2bf(d[2 * p + 1]) << 16);
            *(unsigned int*)((char*)g_xb + (size_t)row * (XST * 2) + (r * 14 + c) * 2) = pack;
        }
    }
    // zero pad k = 196..231 for every row: 9 uint2 per row
    for (int t = blockIdx.x * 256 + threadIdx.x; t < ROWS_TOTAL * 9; t += gridDim.x * 256) {
        int row = t / 9;
        int j   = t - row * 9;
        *(uint2*)((char*)g_xb + (size_t)row * (XST * 2) + 392 + j * 8) = (uint2){0u, 0u};
    }
}

__device__ __forceinline__ void gload_lds16(void* lds, const void* g) {
    __builtin_amdgcn_global_load_lds(
        (const __attribute__((address_space(1))) unsigned int*)g,
        (__attribute__((address_space(3))) unsigned int*)lds, 16, 0, 0);
}

// Block: 64 out rows x 112 out cols; 4 waves, 16 rows each, all 112 cols.
// LDS 79,872 B -> 2 blocks/CU. One barrier per block; staging is pure
// global_load_lds (linear->linear); all ds_reads bank-conflict-free.
__global__ __launch_bounds__(256, 2)
void patch_linear_mfma(const float* __restrict__ blin,
                       float* __restrict__ out) {
    __shared__ __align__(16) char sW[49 * 1024];   // 50176 B, LDS image of one W group
    __shared__ __align__(16) char sX[29 * 1024];   // 29696 B, 64 rows x 464 B

    const int tid  = threadIdx.x;
    const int l    = tid & 63;
    const int wv   = tid >> 6;          // 0..3
    const int lrow = l & 15;
    const int lk   = l >> 4;

    const int rg = blockIdx.x / 7;      // row group (64 rows)
    const int cg = blockIdx.x - rg * 7; // col group (112 cols)

    // ---- stage W group: 49 x 1 KiB, and x rows: 29 x 1 KiB (async DMA) ----
    const char* wsrc = (const char*)g_Wb2 + (size_t)cg * 50176 + l * 16;
    #pragma unroll
    for (int c = 0; c < 13; ++c) {
        int ch = wv + c * 4;
        if (ch < 49) gload_lds16(sW + ch * 1024, wsrc + ch * 1024);
    }
    const char* xsrc = (const char*)g_xb + (size_t)rg * (64 * 464) + l * 16;
    #pragma unroll
    for (int c = 0; c < 8; ++c) {
        int ch = wv + c * 4;
        if (ch < 29) gload_lds16(sX + ch * 1024, xsrc + ch * 1024);
    }

    // acc init = bias: acc[n][j] = blin[cg*112 + n*16 + lk*4 + j]
    f32x4 acc[7];
    #pragma unroll
    for (int n = 0; n < 7; ++n)
        acc[n] = *(const f32x4*)(blin + cg * 112 + n * 16 + lk * 4);

    __syncthreads();   // drains staging; the only barrier

    const char* xb = sX + (wv * 16 + lrow) * 464 + lk * 16;
    const char* wb = sW + lk * 1792 + lrow * 16;   // + kk*7168 + n*256

    #pragma unroll
    for (int kk = 0; kk < 7; ++kk) {
        s16x8 xf = *(const s16x8*)(xb + kk * 64);
        #pragma unroll
        for (int n = 0; n < 7; ++n) {
            s16x8 wf = *(const s16x8*)(wb + kk * 7168 + n * 256);
            acc[n] = __builtin_amdgcn_mfma_f32_16x16x32_bf16(wf, xf, acc[n], 0, 0, 0);
        }
    }

    // ---- store: lane writes 7 x dwordx4; each (row, n) is a full 64-B sector ----
    float* orow = out + (size_t)(rg * 64 + wv * 16 + lrow) * 784 + cg * 112 + lk * 4;
    #pragma unroll
    for (int n = 0; n < 7; ++n)
        *(f32x4*)(orow + n * 16) = acc[n];
}

extern "C" void kernel_launch(void* const* d_in, const int* in_sizes, int n_in,
                              void* d_out, int out_size, void* d_ws, size_t ws_size,
                              hipStream_t stream) {
    const float* x    = (const float*)d_in[0];   // [32768,1,28,28]
    const float* Wlin = (const float*)d_in[1];   // [784,196]
    const float* blin = (const float*)d_in[2];   // [784]
    float* out = (float*)d_out;                  // [32768,4,784]

    prep_w<<<(784 * 56 + 255) / 256, 256, 0, stream>>>(Wlin);
    prep_x<<<4096, 256, 0, stream>>>(x);

    dim3 grid((ROWS_TOTAL / 64) * 7);            // 14336 blocks
    dim3 block(256);
    patch_linear_mfma<<<grid, block, 0, stream>>>(blin, out);
}